// Round 11
// baseline (122.208 us; speedup 1.0000x reference)
//
#include <hip/hip_runtime.h>
#include <hip/hip_bf16.h>
#include <math.h>

#define A_TOTAL 159882
#define NGT 20
#define NBLK 625   // ceil(A_TOTAL/256)
#define WTBLK 288  // extra blocks (x2 imgs) for weight transpose in K1

// level geometry: p6(13) p5(25) p4(50) p3(100) p2(200), 3 anchors/pos
// cumulative anchor offsets: 0, 507, 2382, 9882, 39882, 159882

__device__ __forceinline__ float iou_one(float ax1, float ay1, float ax2, float ay2,
                                         float gx1, float gy1, float gx2, float gy2) {
    float a1 = (ax2 - ax1) * (ay2 - ay1);
    float a2 = (gx2 - gx1) * (gy2 - gy1);
    float ltx = fmaxf(ax1, gx1), lty = fmaxf(ay1, gy1);
    float rbx = fminf(ax2, gx2), rby = fminf(ay2, gy2);
    float w = fmaxf(rbx - ltx, 0.f), h = fmaxf(rby - lty, 0.f);
    float inter = w * h;
    return inter / (a1 + a2 - inter);
}

__device__ __forceinline__ void decode_anchor(int a, int& W, int& aid, int& y, int& x, int& lvl) {
    int off;
    if      (a < 507)   { off = 0;     W = 13;  lvl = 0; }
    else if (a < 2382)  { off = 507;   W = 25;  lvl = 1; }
    else if (a < 9882)  { off = 2382;  W = 50;  lvl = 2; }
    else if (a < 39882) { off = 9882;  W = 100; lvl = 3; }
    else                { off = 39882; W = 200; lvl = 4; }
    int rel = a - off;
    aid = rel % 3;
    int pos = rel / 3;
    y = pos / W; x = pos % W;
}

// ============ K1: wtrans ∥ bmax + mv/aux; last bmax block per image does bred ============
__global__ __launch_bounds__(256) void k1_fused(
    const float* __restrict__ anchors, const float* __restrict__ gt,
    const float* __restrict__ w_in,
    float* __restrict__ pmax, float* __restrict__ mv, unsigned* __restrict__ aux,
    float* __restrict__ wt, unsigned int* __restrict__ best,
    unsigned* __restrict__ ctr) {
    const int bx = blockIdx.x, img = blockIdx.y;
    const int tid = threadIdx.x;
    if (bx >= NBLK) {
        int idx = ((bx - NBLK) * 2 + img) * 256 + tid;   // 0..147455
        int co = idx / 576, k4 = idx - co * 576;
        float4 v = *(const float4*)(w_in + (size_t)co * 2304 + k4 * 4);
        ((float4*)wt)[(size_t)k4 * 256 + co] = v;
        return;
    }
    __shared__ float sgt[NGT * 4];
    __shared__ float sred[4][NGT];
    __shared__ float pblk[NGT];
    __shared__ int sdone;
    if (tid < NGT * 4) sgt[tid] = gt[img * NGT * 4 + tid];
    __syncthreads();
    const int a = bx * 256 + tid;
    const bool act = a < A_TOTAL;
    float4 ab = make_float4(0.f, 0.f, 1.f, 1.f);
    if (act) ab = ((const float4*)anchors)[a];
    const int lane = tid & 63, wid = tid >> 6;
    float v[NGT];
    float mval = -1.f; int arg = 0;
    #pragma unroll
    for (int g = 0; g < NGT; g++) {
        float u = act ? iou_one(ab.x, ab.y, ab.z, ab.w,
                                sgt[g*4], sgt[g*4+1], sgt[g*4+2], sgt[g*4+3]) : 0.f;
        v[g] = u;
        if (u > mval) { mval = u; arg = g; }
    }
    #pragma unroll
    for (int g = 0; g < NGT; g++) {
        float u = v[g];
        #pragma unroll
        for (int o = 32; o > 0; o >>= 1) u = fmaxf(u, __shfl_down(u, o));
        if (lane == 0) sred[wid][g] = u;
    }
    __syncthreads();
    if (tid < NGT) {
        float u = fmaxf(fmaxf(sred[0][tid], sred[1][tid]),
                        fmaxf(sred[2][tid], sred[3][tid]));
        pblk[tid] = u;
        pmax[((size_t)img * NBLK + bx) * NGT + tid] = u;
    }
    __syncthreads();
    if (act) {
        unsigned mask = 0;
        #pragma unroll
        for (int g = 0; g < NGT; g++)
            if (v[g] == pblk[g] && v[g] > 0.f) mask |= (1u << g);
        mv[(size_t)img * A_TOTAL + a] = mval;
        aux[(size_t)img * A_TOTAL + a] = (mask << 5) | (unsigned)arg;
    }
    // last-block pattern: producers release, last arriver does the global reduce.
    __syncthreads();                       // all stores issued+completed (vmcnt0 at barrier)
    if (tid == 0) {
        __threadfence();                   // release: wb this XCD's L2 to device point
        int d = (atomicAdd(&ctr[img], 1u) == (unsigned)(NBLK - 1));
        sdone = d;
        if (d) __threadfence();            // acquire: invalidate stale L1/L2 lines
    }
    __syncthreads();
    if (sdone) {
        #pragma unroll 1
        for (int g = 0; g < NGT; g++) {
            float u = 0.f;
            for (int i = tid; i < NBLK; i += 256)
                u = fmaxf(u, pmax[((size_t)img * NBLK + i) * NGT + g]);
            #pragma unroll
            for (int o = 32; o > 0; o >>= 1) u = fmaxf(u, __shfl_down(u, o));
            if (lane == 0) sred[wid][g] = u;
        }
        __syncthreads();
        if (tid < NGT)
            best[img * NGT + tid] = __float_as_uint(
                fmaxf(fmaxf(sred[0][tid], sred[1][tid]),
                      fmaxf(sred[2][tid], sred[3][tid])));
    }
}

// ============ K2: label from stored mv/aux (round-10 proven) ============
__global__ __launch_bounds__(256) void k2_label(
    const float* __restrict__ mv, const unsigned* __restrict__ aux,
    const float* __restrict__ pmax, const unsigned int* __restrict__ best,
    unsigned char* __restrict__ packed, unsigned int* __restrict__ blk_cnt) {
    const int img = blockIdx.y, blk = blockIdx.x;
    const int tid = threadIdx.x;
    const int lane = tid & 63, wid = tid >> 6;
    __shared__ float sbest[NGT], pblk[NGT];
    __shared__ int wp[4], wn[4];
    if (tid < NGT) {
        sbest[tid] = __uint_as_float(best[img * NGT + tid]);
        pblk[tid]  = pmax[((size_t)img * NBLK + blk) * NGT + tid];
    }
    __syncthreads();
    const int a = blk * 256 + tid;
    const bool act = a < A_TOTAL;
    int code = 2;
    if (act) {
        float mval = mv[(size_t)img * A_TOTAL + a];
        unsigned ax = aux[(size_t)img * A_TOTAL + a];
        unsigned mask = ax >> 5;
        bool lq = false;
        #pragma unroll
        for (int g = 0; g < NGT; g++)
            if (((mask >> g) & 1u) && (pblk[g] == sbest[g])) lq = true;
        if (lq || mval >= 0.7f) code = 1;
        else if (mval < 0.3f)   code = 0;
        packed[(size_t)img * A_TOTAL + a] = (unsigned char)((code << 5) | (ax & 31u));
    }
    unsigned long long bp = __ballot(act && code == 1);
    unsigned long long bn = __ballot(act && code == 0);
    if (lane == 0) { wp[wid] = __popcll(bp); wn[wid] = __popcll(bn); }
    __syncthreads();
    if (tid == 0) {
        unsigned int p = wp[0] + wp[1] + wp[2] + wp[3];
        unsigned int n = wn[0] + wn[1] + wn[2] + wn[3];
        blk_cnt[img * NBLK + blk] = (p << 16) | n;
    }
}

// ============ K3: select + per-block self-prefix (round-9/10 proven) ============
__global__ __launch_bounds__(256) void k3_select(
    const unsigned char* __restrict__ packed,
    const unsigned int* __restrict__ blk_cnt,
    int* __restrict__ sel, int* __restrict__ sel_count) {
    const int img = blockIdx.y, blk = blockIdx.x;
    const int tid = threadIdx.x;
    const int lane = tid & 63, wid = tid >> 6;
    __shared__ unsigned long long sscan[8];
    __shared__ int wcnt[8];

    unsigned long long tot = 0ULL, pre = 0ULL;
    const int j0 = tid * 3;
    #pragma unroll
    for (int j = 0; j < 3; j++) {
        int i = j0 + j;
        if (i < NBLK) {
            unsigned u = blk_cnt[img * NBLK + i];
            unsigned long long w = ((unsigned long long)(u >> 16) << 32) | (u & 0xFFFFu);
            tot += w;
            if (i < blk) pre += w;
        }
    }
    #pragma unroll
    for (int o = 32; o > 0; o >>= 1) {
        tot += __shfl_down(tot, o);
        pre += __shfl_down(pre, o);
    }
    if (lane == 0) { sscan[wid] = tot; sscan[4 + wid] = pre; }
    __syncthreads();
    unsigned long long tota = sscan[0] + sscan[1] + sscan[2] + sscan[3];
    unsigned long long prea = sscan[4] + sscan[5] + sscan[6] + sscan[7];
    int tp = (int)(tota >> 32), tn = (int)(tota & 0xFFFFFFFFull);
    int npos = min(tp, 128), capn = 256 - npos;
    if (blk == 0 && tid == 0) sel_count[img] = npos + min(tn, capn);
    int base_p = (int)(prea >> 32), base_n = (int)(prea & 0xFFFFFFFFull);

    const int a = blk * 256 + tid;
    const bool act = a < A_TOTAL;
    int code = act ? (packed[(size_t)img * A_TOTAL + a] >> 5) : 2;
    const bool isp = act && code == 1;
    const bool isn = act && code == 0;
    unsigned long long bp = __ballot(isp);
    unsigned long long bn = __ballot(isn);
    if (lane == 0) { wcnt[wid] = __popcll(bp); wcnt[4 + wid] = __popcll(bn); }
    __syncthreads();
    const unsigned long long mlt = (1ULL << lane) - 1ULL;
    int rp = __popcll(bp & mlt), rn = __popcll(bn & mlt);
    for (int w = 0; w < 4; w++)
        if (w < wid) { rp += wcnt[w]; rn += wcnt[4 + w]; }
    if (isp) { int r = base_p + rp; if (r < npos) sel[img * 256 + r] = a | (1 << 30); }
    if (isn) { int r = base_n + rn; if (r < capn) sel[img * 256 + npos + r] = a; }
}

// ============ K4: conv partials — 16 anchors x 16-ci chunk (TRM=144) per block ============
__global__ __launch_bounds__(256) void k_convT16A(
    const float* __restrict__ f0, const float* __restrict__ f1,
    const float* __restrict__ f2, const float* __restrict__ f3,
    const float* __restrict__ f4,
    const float* __restrict__ wt,
    const int* __restrict__ sel, const int* __restrict__ sel_count,
    float* __restrict__ xpart) {
    const int img = blockIdx.z;          // grid (16, 16, 2)
    const int chunk = blockIdx.y;
    const int slot0 = blockIdx.x * 16;
    const int nsel = sel_count[img];
    if (slot0 >= nsel) return;

    __shared__ __align__(16) float patch[16][144];   // 9216 B
    __shared__ int sW[16], sY[16], sX[16], sAct[16];
    __shared__ const float* sfm[16];
    const int tid = threadIdx.x;

    if (tid < 16) {
        int slot = slot0 + tid;
        bool act = slot < nsel;
        int e = act ? sel[img * 256 + slot] : 0;
        int a = e & 0x3FFFFFFF;
        int W, aid, y, x, lvl;
        decode_anchor(a, W, aid, y, x, lvl);
        sW[tid] = W; sY[tid] = y; sX[tid] = x; sAct[tid] = act ? 1 : 0;
        sfm[tid] = (lvl == 0 ? f0 : lvl == 1 ? f1 : lvl == 2 ? f2 : lvl == 3 ? f3 : f4);
    }
    __syncthreads();

    for (int p = tid; p < 16 * 144; p += 256) {
        int aa = p / 144;
        int idx = p - aa * 144;
        int cil = idx / 9;
        int r = idx - cil * 9;
        int ky = r / 3, kx = r - ky * 3;
        int W = sW[aa];
        int yy = sY[aa] + ky - 1, xx = sX[aa] + kx - 1;
        float v = 0.f;
        if (sAct[aa] && yy >= 0 && yy < W && xx >= 0 && xx < W) {
            int ci = chunk * 16 + cil;
            v = sfm[aa][(((size_t)img * 256 + ci) * W + yy) * W + xx];
        }
        patch[aa][idx] = v;
    }
    __syncthreads();

    const int c = tid;
    const float4* wt4 = (const float4*)wt + (size_t)(chunk * 36) * 256 + c;
    float acc[16];
    #pragma unroll
    for (int aa = 0; aa < 16; aa++) acc[aa] = 0.f;
    #pragma unroll 2
    for (int i = 0; i < 36; i++) {
        float4 w = wt4[(size_t)i * 256];     // 1KB contiguous per wave
        #pragma unroll
        for (int aa = 0; aa < 16; aa++) {
            float4 q = ((const float4*)patch[aa])[i];   // uniform addr -> broadcast
            acc[aa] += w.x * q.x + w.y * q.y + w.z * q.z + w.w * q.w;
        }
    }
    #pragma unroll
    for (int aa = 0; aa < 16; aa++) {
        int slot = slot0 + aa;
        if (slot < nsel)
            xpart[(((size_t)img * 16 + chunk) * 256 + slot) * 256 + c] = acc[aa];
    }
}

// ============ K5: post (reduce 16 chunks + heads + losses); last block does final ============
__global__ __launch_bounds__(256) void k_post_final(
    const float* __restrict__ xpart,
    const float* __restrict__ anchors, const float* __restrict__ gt,
    const float* __restrict__ b_in,
    const float* __restrict__ w_obj, const float* __restrict__ b_obj,
    const float* __restrict__ w_del, const float* __restrict__ b_del,
    const unsigned char* __restrict__ packed,
    const int* __restrict__ sel, const int* __restrict__ sel_count,
    float* __restrict__ lossbuf, float* __restrict__ out,
    unsigned* __restrict__ ctr) {
    const int img = blockIdx.y;
    const int slot = blockIdx.x;
    const int nsel = sel_count[img];
    const int c = threadIdx.x;
    const int lane = c & 63, wid = c >> 6;
    __shared__ float red[5][4];
    __shared__ int sdone;
    __shared__ float rb[4], rl[4];

    if (slot < nsel) {                          // block-uniform condition
        const int e = sel[img * 256 + slot];
        const int is_pos = (e >> 30) & 1;
        const int a = e & 0x3FFFFFFF;
        int W, aid, y, x, lvl;
        decode_anchor(a, W, aid, y, x, lvl);

        float s = b_in[c];
        #pragma unroll
        for (int ch = 0; ch < 16; ch++)
            s += xpart[(((size_t)img * 16 + ch) * 256 + slot) * 256 + c];
        float xf = fmaxf(s, 0.f);

        float part[5];
        part[0] = xf * w_obj[aid * 256 + c];
        #pragma unroll
        for (int j = 0; j < 4; j++) part[1 + j] = xf * w_del[(aid * 4 + j) * 256 + c];
        #pragma unroll
        for (int o = 32; o > 0; o >>= 1)
            #pragma unroll
            for (int j = 0; j < 5; j++) part[j] += __shfl_down(part[j], o);
        if (lane == 0)
            #pragma unroll
            for (int j = 0; j < 5; j++) red[j][wid] = part[j];
        __syncthreads();

        if (c == 0) {
            float logit = red[0][0] + red[0][1] + red[0][2] + red[0][3] + b_obj[aid];
            float tgt = is_pos ? 1.f : 0.f;
            float bce = fmaxf(logit, 0.f) - logit * tgt + log1pf(expf(-fabsf(logit)));
            float l1 = 0.f;
            if (is_pos) {
                float d[4];
                #pragma unroll
                for (int j = 0; j < 4; j++)
                    d[j] = red[1 + j][0] + red[1 + j][1] + red[1 + j][2] + red[1 + j][3]
                           + b_del[aid * 4 + j];
                int m = packed[(size_t)img * A_TOTAL + a] & 31;
                const float* sp = anchors + (size_t)a * 4;
                const float* t = gt + (size_t)(img * NGT + m) * 4;
                float sw = sp[2] - sp[0], sh = sp[3] - sp[1];
                float scx = sp[0] + 0.5f * sw, scy = sp[1] + 0.5f * sh;
                float tw = t[2] - t[0], th = t[3] - t[1];
                float tcx = t[0] + 0.5f * tw, tcy = t[1] + 0.5f * th;
                float g0 = (tcx - scx) / sw, g1 = (tcy - scy) / sh;
                float g2 = logf(tw / sw),    g3 = logf(th / sh);
                l1 = fabsf(d[0]-g0) + fabsf(d[1]-g1) + fabsf(d[2]-g2) + fabsf(d[3]-g3);
            }
            lossbuf[(img * 256 + slot) * 2 + 0] = bce;
            lossbuf[(img * 256 + slot) * 2 + 1] = l1;
        }
    }
    // last-block final reduction (all 512 blocks increment; threshold data-independent)
    __syncthreads();
    if (c == 0) {
        __threadfence();
        int d = (atomicAdd(ctr, 1u) == 511u);
        sdone = d;
        if (d) __threadfence();
    }
    __syncthreads();
    if (sdone) {
        int n0 = sel_count[0], n1 = sel_count[1];
        float bce = 0.f, l1 = 0.f;
        for (int e2 = c; e2 < 512; e2 += 256) {
            int i2 = e2 >> 8, s2 = e2 & 255;
            if (s2 < (i2 ? n1 : n0)) {
                bce += lossbuf[e2 * 2 + 0];
                l1  += lossbuf[e2 * 2 + 1];
            }
        }
        #pragma unroll
        for (int o = 32; o > 0; o >>= 1) {
            bce += __shfl_down(bce, o);
            l1  += __shfl_down(l1, o);
        }
        if (lane == 0) { rb[wid] = bce; rl[wid] = l1; }
        __syncthreads();
        if (c == 0) {
            out[0] = 0.5f * (rb[0] + rb[1] + rb[2] + rb[3]);
            out[1] = 0.5f * (rl[0] + rl[1] + rl[2] + rl[3]);
        }
    }
}

// ============ minimal fallback (round-3 proven) for tiny workspace ============
__global__ void k_init(unsigned int* best, float* out) {
    int t = threadIdx.x;
    if (t < 2 * NGT) best[t] = 0u;
    if (t < 2) out[t] = 0.f;
}

__global__ void k_best(const float* __restrict__ anchors, const float* __restrict__ gt,
                       unsigned int* best) {
    const int img = blockIdx.y;
    __shared__ float sgt[NGT * 4];
    __shared__ float sred[4][NGT];
    const int tid = threadIdx.x;
    if (tid < NGT * 4) sgt[tid] = gt[img * NGT * 4 + tid];
    __syncthreads();
    float vmax[NGT];
    #pragma unroll
    for (int g = 0; g < NGT; g++) vmax[g] = 0.f;
    const int stride = gridDim.x * blockDim.x;
    for (int a = blockIdx.x * blockDim.x + tid; a < A_TOTAL; a += stride) {
        float4 ab = ((const float4*)anchors)[a];
        #pragma unroll
        for (int g = 0; g < NGT; g++) {
            float v = iou_one(ab.x, ab.y, ab.z, ab.w,
                              sgt[g * 4], sgt[g * 4 + 1], sgt[g * 4 + 2], sgt[g * 4 + 3]);
            vmax[g] = fmaxf(vmax[g], v);
        }
    }
    const int lane = tid & 63, wid = tid >> 6;
    #pragma unroll
    for (int g = 0; g < NGT; g++) {
        float v = vmax[g];
        #pragma unroll
        for (int o = 32; o > 0; o >>= 1) v = fmaxf(v, __shfl_down(v, o));
        if (lane == 0) sred[wid][g] = v;
    }
    __syncthreads();
    if (tid < NGT) {
        float v = fmaxf(fmaxf(sred[0][tid], sred[1][tid]),
                        fmaxf(sred[2][tid], sred[3][tid]));
        atomicMax(&best[img * NGT + tid], __float_as_uint(v));
    }
}

__global__ void k_label_old(const float* __restrict__ anchors, const float* __restrict__ gt,
                            const unsigned int* __restrict__ best,
                            unsigned char* packed, unsigned int* blk_cnt) {
    const int img = blockIdx.y;
    __shared__ float sgt[NGT * 4];
    __shared__ unsigned int sbest[NGT];
    __shared__ int wp[4], wn[4];
    const int tid = threadIdx.x;
    if (tid < NGT * 4) sgt[tid] = gt[img * NGT * 4 + tid];
    if (tid < NGT) sbest[tid] = best[img * NGT + tid];
    __syncthreads();
    const int a = blockIdx.x * blockDim.x + tid;
    const bool act = a < A_TOTAL;
    int code = 2;
    if (act) {
        float4 ab = ((const float4*)anchors)[a];
        float mval = -1.f; int arg = 0; bool lq = false;
        #pragma unroll
        for (int g = 0; g < NGT; g++) {
            float v = iou_one(ab.x, ab.y, ab.z, ab.w,
                              sgt[g * 4], sgt[g * 4 + 1], sgt[g * 4 + 2], sgt[g * 4 + 3]);
            if (v > mval) { mval = v; arg = g; }
            if (__float_as_uint(v) == sbest[g] && v > 0.f) lq = true;
        }
        if (lq || mval >= 0.7f) code = 1;
        else if (mval < 0.3f)   code = 0;
        packed[(size_t)img * A_TOTAL + a] = (unsigned char)((code << 5) | arg);
    }
    unsigned long long bp = __ballot(act && code == 1);
    unsigned long long bn = __ballot(act && code == 0);
    const int lane = tid & 63, wid = tid >> 6;
    if (lane == 0) { wp[wid] = __popcll(bp); wn[wid] = __popcll(bn); }
    __syncthreads();
    if (tid == 0) {
        unsigned int p = wp[0] + wp[1] + wp[2] + wp[3];
        unsigned int n = wn[0] + wn[1] + wn[2] + wn[3];
        blk_cnt[img * NBLK + blockIdx.x] = (p << 16) | n;
    }
}

__global__ __launch_bounds__(256) void k_eval(
    const float* __restrict__ f0, const float* __restrict__ f1,
    const float* __restrict__ f2, const float* __restrict__ f3,
    const float* __restrict__ f4,
    const float* __restrict__ anchors, const float* __restrict__ gt,
    const float* __restrict__ w_in, const float* __restrict__ b_in,
    const float* __restrict__ w_obj, const float* __restrict__ b_obj,
    const float* __restrict__ w_del, const float* __restrict__ b_del,
    const unsigned char* __restrict__ packed,
    const int* __restrict__ sel, const int* __restrict__ sel_count,
    float* out) {
    const int img = blockIdx.x >> 6;
    const int slot0 = (blockIdx.x & 63) * 4;
    const int nsel = sel_count[img];
    if (slot0 >= nsel) return;

    __shared__ __align__(16) float patch[4][2304];
    __shared__ float red[4][5][4];
    __shared__ float lsum[2];
    const int c = threadIdx.x;
    if (c < 2) lsum[c] = 0.f;

    bool actv[4]; int av[4], aidv[4], isposv[4];
    #pragma unroll
    for (int aa = 0; aa < 4; aa++) {
        int slot = slot0 + aa;
        bool act = slot < nsel;
        actv[aa] = act;
        int e = act ? sel[img * 256 + slot] : 0;
        isposv[aa] = (e >> 30) & 1;
        int a = e & 0x3FFFFFFF;
        av[aa] = a;
        int W, aid, y, x, lvl;
        decode_anchor(a, W, aid, y, x, lvl);
        aidv[aa] = aid;
        const float* fm = lvl == 0 ? f0 : lvl == 1 ? f1 : lvl == 2 ? f2 : lvl == 3 ? f3 : f4;
        const float* ch = fm + ((size_t)img * 256 + c) * W * W;
        #pragma unroll
        for (int ky = 0; ky < 3; ky++)
            #pragma unroll
            for (int kx = 0; kx < 3; kx++) {
                int yy = y + ky - 1, xx = x + kx - 1;
                float v = (act && yy >= 0 && yy < W && xx >= 0 && xx < W) ? ch[yy * W + xx] : 0.f;
                patch[aa][c * 9 + ky * 3 + kx] = v;
            }
    }
    __syncthreads();

    const float bi = b_in[c];
    float acc0 = bi, acc1 = bi, acc2 = bi, acc3 = bi;
    const float4* wr = (const float4*)(w_in + (size_t)c * 2304);
    const float4* p0 = (const float4*)patch[0];
    const float4* p1 = (const float4*)patch[1];
    const float4* p2 = (const float4*)patch[2];
    const float4* p3 = (const float4*)patch[3];
    #pragma unroll 4
    for (int i = 0; i < 576; i++) {
        float4 w = wr[i];
        float4 q;
        q = p0[i]; acc0 += w.x * q.x + w.y * q.y + w.z * q.z + w.w * q.w;
        q = p1[i]; acc1 += w.x * q.x + w.y * q.y + w.z * q.z + w.w * q.w;
        q = p2[i]; acc2 += w.x * q.x + w.y * q.y + w.z * q.z + w.w * q.w;
        q = p3[i]; acc3 += w.x * q.x + w.y * q.y + w.z * q.z + w.w * q.w;
    }
    float xf[4] = { fmaxf(acc0, 0.f), fmaxf(acc1, 0.f), fmaxf(acc2, 0.f), fmaxf(acc3, 0.f) };

    float part[4][5];
    #pragma unroll
    for (int aa = 0; aa < 4; aa++) {
        part[aa][0] = xf[aa] * w_obj[aidv[aa] * 256 + c];
        #pragma unroll
        for (int j = 0; j < 4; j++)
            part[aa][1 + j] = xf[aa] * w_del[(aidv[aa] * 4 + j) * 256 + c];
    }
    const int lane = c & 63, wid = c >> 6;
    #pragma unroll
    for (int o = 32; o > 0; o >>= 1)
        #pragma unroll
        for (int aa = 0; aa < 4; aa++)
            #pragma unroll
            for (int j = 0; j < 5; j++)
                part[aa][j] += __shfl_down(part[aa][j], o);
    if (lane == 0)
        #pragma unroll
        for (int aa = 0; aa < 4; aa++)
            #pragma unroll
            for (int j = 0; j < 5; j++)
                red[aa][j][wid] = part[aa][j];
    __syncthreads();

    if (c < 4 && actv[c]) {
        const int aa = c;
        float logit = red[aa][0][0] + red[aa][0][1] + red[aa][0][2] + red[aa][0][3] + b_obj[aidv[aa]];
        float tgt = isposv[aa] ? 1.f : 0.f;
        float bce = fmaxf(logit, 0.f) - logit * tgt + log1pf(expf(-fabsf(logit)));
        atomicAdd(&lsum[0], bce);
        if (isposv[aa]) {
            float d[4];
            #pragma unroll
            for (int j = 0; j < 4; j++)
                d[j] = red[aa][1 + j][0] + red[aa][1 + j][1] + red[aa][1 + j][2] + red[aa][1 + j][3]
                       + b_del[aidv[aa] * 4 + j];
            int a = av[aa];
            int m = packed[(size_t)img * A_TOTAL + a] & 31;
            const float* s = anchors + (size_t)a * 4;
            const float* t = gt + (size_t)(img * NGT + m) * 4;
            float sw = s[2] - s[0], sh = s[3] - s[1];
            float scx = s[0] + 0.5f * sw, scy = s[1] + 0.5f * sh;
            float tw = t[2] - t[0], th = t[3] - t[1];
            float tcx = t[0] + 0.5f * tw, tcy = t[1] + 0.5f * th;
            float g0 = (tcx - scx) / sw, g1 = (tcy - scy) / sh;
            float g2 = logf(tw / sw),    g3 = logf(th / sh);
            float l1 = fabsf(d[0] - g0) + fabsf(d[1] - g1) + fabsf(d[2] - g2) + fabsf(d[3] - g3);
            atomicAdd(&lsum[1], l1);
        }
    }
    __syncthreads();
    if (c == 0) {
        atomicAdd(&out[0], 0.5f * lsum[0]);
        atomicAdd(&out[1], 0.5f * lsum[1]);
    }
}

extern "C" void kernel_launch(void* const* d_in, const int* in_sizes, int n_in,
                              void* d_out, int out_size, void* d_ws, size_t ws_size,
                              hipStream_t stream) {
    const float* f_p6 = (const float*)d_in[0];
    const float* f_p5 = (const float*)d_in[1];
    const float* f_p4 = (const float*)d_in[2];
    const float* f_p3 = (const float*)d_in[3];
    const float* f_p2 = (const float*)d_in[4];
    const float* anchors = (const float*)d_in[5];
    const float* gt      = (const float*)d_in[6];
    const float* w_in  = (const float*)d_in[7];
    const float* b_in  = (const float*)d_in[8];
    const float* w_obj = (const float*)d_in[9];
    const float* b_obj = (const float*)d_in[10];
    const float* w_del = (const float*)d_in[11];
    const float* b_del = (const float*)d_in[12];
    float* out = (float*)d_out;
    char* ws = (char*)d_ws;

    // workspace layout (round-10 offsets + counters in the 7296..17344 gap)
    unsigned int* best    = (unsigned int*)(ws + 0);        // 160 B
    int* sel_count        = (int*)(ws + 168);               // 8 B
    int* sel              = (int*)(ws + 192);               // 2048 B
    unsigned int* blk_cnt = (unsigned int*)(ws + 2240);     // 5000 B
    unsigned* ctrs        = (unsigned*)(ws + 7296);         // [0,1]=K1 per-img, [2]=post
    unsigned char* packed = (unsigned char*)(ws + 17344);   // 319764 B
    float* lossbuf        = (float*)(ws + 337152);          // 4096 B
    float* mv             = (float*)(ws + 341248);          // 1279056 B
    unsigned* aux         = (unsigned*)(ws + 1620352);      // 1279056 B
    float* pmax           = (float*)(ws + 2899456);         // 100000 B
    float* xpart          = (float*)(ws + 2999552);         // 16*2*256*256*4 = 8388608 B
    float* wt             = (float*)(ws + 11388160);        // 2359296 B
    const size_t WS_NEED  = 13747456;

    if (ws_size >= WS_NEED) {
        // 6 dispatches. Round-8 lesson: NO spinning grid barriers; last-block
        // pattern (fence + device atomic, no spin) replaces bred/final launches.
        hipMemsetAsync(ctrs, 0, 16, stream);
        k1_fused<<<dim3(NBLK + WTBLK, 2), 256, 0, stream>>>(anchors, gt, w_in,
                                                            pmax, mv, aux, wt, best, ctrs);
        k2_label<<<dim3(NBLK, 2), 256, 0, stream>>>(mv, aux, pmax, best, packed, blk_cnt);
        k3_select<<<dim3(NBLK, 2), 256, 0, stream>>>(packed, blk_cnt, sel, sel_count);
        k_convT16A<<<dim3(16, 16, 2), 256, 0, stream>>>(f_p6, f_p5, f_p4, f_p3, f_p2,
                                                        wt, sel, sel_count, xpart);
        k_post_final<<<dim3(256, 2), 256, 0, stream>>>(xpart, anchors, gt, b_in,
                                                       w_obj, b_obj, w_del, b_del,
                                                       packed, sel, sel_count,
                                                       lossbuf, out, ctrs + 2);
    } else {
        // tiny-workspace fallback (round-3 proven)
        k_init<<<1, 64, 0, stream>>>(best, out);
        k_best<<<dim3(64, 2), 256, 0, stream>>>(anchors, gt, best);
        k_label_old<<<dim3(NBLK, 2), 256, 0, stream>>>(anchors, gt, best, packed, blk_cnt);
        k3_select<<<dim3(NBLK, 2), 256, 0, stream>>>(packed, blk_cnt, sel, sel_count);
        k_eval<<<128, 256, 0, stream>>>(f_p6, f_p5, f_p4, f_p3, f_p2,
                                        anchors, gt, w_in, b_in, w_obj, b_obj,
                                        w_del, b_del, packed, sel, sel_count, out);
    }
}

// Round 12
// 69.711 us; speedup vs baseline: 1.7531x; 1.7531x over previous
//
#include <hip/hip_runtime.h>
#include <hip/hip_bf16.h>
#include <math.h>

#define A_TOTAL 159882
#define NGT 20
#define NBLK 625   // ceil(A_TOTAL/256)
#define WTBLK 288  // extra blocks (x2 imgs) for weight transpose in K1

// level geometry: p6(13) p5(25) p4(50) p3(100) p2(200), 3 anchors/pos
// cumulative anchor offsets: 0, 507, 2382, 9882, 39882, 159882

__device__ __forceinline__ float iou_one(float ax1, float ay1, float ax2, float ay2,
                                         float gx1, float gy1, float gx2, float gy2) {
    float a1 = (ax2 - ax1) * (ay2 - ay1);
    float a2 = (gx2 - gx1) * (gy2 - gy1);
    float ltx = fmaxf(ax1, gx1), lty = fmaxf(ay1, gy1);
    float rbx = fminf(ax2, gx2), rby = fminf(ay2, gy2);
    float w = fmaxf(rbx - ltx, 0.f), h = fmaxf(rby - lty, 0.f);
    float inter = w * h;
    return inter / (a1 + a2 - inter);
}

__device__ __forceinline__ void decode_anchor(int a, int& W, int& aid, int& y, int& x, int& lvl) {
    int off;
    if      (a < 507)   { off = 0;     W = 13;  lvl = 0; }
    else if (a < 2382)  { off = 507;   W = 25;  lvl = 1; }
    else if (a < 9882)  { off = 2382;  W = 50;  lvl = 2; }
    else if (a < 39882) { off = 9882;  W = 100; lvl = 3; }
    else                { off = 39882; W = 200; lvl = 4; }
    int rel = a - off;
    aid = rel % 3;
    int pos = rel / 3;
    y = pos / W; x = pos % W;
}

// ============ K1: wtrans (blocks >= NBLK) ∥ bmax + per-anchor mv/aux (blocks < NBLK) ============
// NOTE (round-11 lesson): NO per-block __threadfence/last-block patterns — a
// device-scope fence per block costs ~50 µs at 1250 blocks on MI355X. Kernel
// launch boundaries are the cheap sync primitive (~2 µs each).
__global__ __launch_bounds__(256) void k1_bmax_wtrans(
    const float* __restrict__ anchors, const float* __restrict__ gt,
    const float* __restrict__ w_in,
    float* __restrict__ pmax, float* __restrict__ mv, unsigned* __restrict__ aux,
    float* __restrict__ wt) {
    const int bx = blockIdx.x, img = blockIdx.y;
    const int tid = threadIdx.x;
    if (bx >= NBLK) {
        int idx = ((bx - NBLK) * 2 + img) * 256 + tid;   // 0..147455
        int co = idx / 576, k4 = idx - co * 576;
        float4 v = *(const float4*)(w_in + (size_t)co * 2304 + k4 * 4);
        ((float4*)wt)[(size_t)k4 * 256 + co] = v;
        return;
    }
    __shared__ float sgt[NGT * 4];
    __shared__ float sred[4][NGT];
    __shared__ float pblk[NGT];
    if (tid < NGT * 4) sgt[tid] = gt[img * NGT * 4 + tid];
    __syncthreads();
    const int a = bx * 256 + tid;
    const bool act = a < A_TOTAL;
    float4 ab = make_float4(0.f, 0.f, 1.f, 1.f);
    if (act) ab = ((const float4*)anchors)[a];
    const int lane = tid & 63, wid = tid >> 6;
    float v[NGT];
    float mval = -1.f; int arg = 0;
    #pragma unroll
    for (int g = 0; g < NGT; g++) {
        float u = act ? iou_one(ab.x, ab.y, ab.z, ab.w,
                                sgt[g*4], sgt[g*4+1], sgt[g*4+2], sgt[g*4+3]) : 0.f;
        v[g] = u;
        if (u > mval) { mval = u; arg = g; }
    }
    #pragma unroll
    for (int g = 0; g < NGT; g++) {
        float u = v[g];
        #pragma unroll
        for (int o = 32; o > 0; o >>= 1) u = fmaxf(u, __shfl_down(u, o));
        if (lane == 0) sred[wid][g] = u;
    }
    __syncthreads();
    if (tid < NGT) {
        float u = fmaxf(fmaxf(sred[0][tid], sred[1][tid]),
                        fmaxf(sred[2][tid], sred[3][tid]));
        pblk[tid] = u;
        pmax[((size_t)img * NBLK + bx) * NGT + tid] = u;
    }
    __syncthreads();
    if (act) {
        unsigned mask = 0;
        #pragma unroll
        for (int g = 0; g < NGT; g++)
            if (v[g] == pblk[g] && v[g] > 0.f) mask |= (1u << g);
        mv[(size_t)img * A_TOTAL + a] = mval;
        aux[(size_t)img * A_TOTAL + a] = (mask << 5) | (unsigned)arg;
    }
}

// ============ K1b: tree-reduce 625 partials per (img, gt) -> best ============
__global__ void k_bred(const float* __restrict__ pmax, unsigned int* __restrict__ best) {
    const int g = blockIdx.x, img = blockIdx.y;
    const int tid = threadIdx.x;   // 256
    float v = 0.f;
    for (int i = tid; i < NBLK; i += 256)
        v = fmaxf(v, pmax[((size_t)img * NBLK + i) * NGT + g]);
    const int lane = tid & 63, wid = tid >> 6;
    #pragma unroll
    for (int o = 32; o > 0; o >>= 1) v = fmaxf(v, __shfl_down(v, o));
    __shared__ float r[4];
    if (lane == 0) r[wid] = v;
    __syncthreads();
    if (tid == 0)
        best[img * NGT + g] = __float_as_uint(fmaxf(fmaxf(r[0], r[1]), fmaxf(r[2], r[3])));
}

// ============ K2: label from stored mv/aux (round-10 proven) ============
__global__ __launch_bounds__(256) void k2_label(
    const float* __restrict__ mv, const unsigned* __restrict__ aux,
    const float* __restrict__ pmax, const unsigned int* __restrict__ best,
    unsigned char* __restrict__ packed, unsigned int* __restrict__ blk_cnt) {
    const int img = blockIdx.y, blk = blockIdx.x;
    const int tid = threadIdx.x;
    const int lane = tid & 63, wid = tid >> 6;
    __shared__ float sbest[NGT], pblk[NGT];
    __shared__ int wp[4], wn[4];
    if (tid < NGT) {
        sbest[tid] = __uint_as_float(best[img * NGT + tid]);
        pblk[tid]  = pmax[((size_t)img * NBLK + blk) * NGT + tid];
    }
    __syncthreads();
    const int a = blk * 256 + tid;
    const bool act = a < A_TOTAL;
    int code = 2;
    if (act) {
        float mval = mv[(size_t)img * A_TOTAL + a];
        unsigned ax = aux[(size_t)img * A_TOTAL + a];
        unsigned mask = ax >> 5;
        bool lq = false;
        #pragma unroll
        for (int g = 0; g < NGT; g++)
            if (((mask >> g) & 1u) && (pblk[g] == sbest[g])) lq = true;
        if (lq || mval >= 0.7f) code = 1;
        else if (mval < 0.3f)   code = 0;
        packed[(size_t)img * A_TOTAL + a] = (unsigned char)((code << 5) | (ax & 31u));
    }
    unsigned long long bp = __ballot(act && code == 1);
    unsigned long long bn = __ballot(act && code == 0);
    if (lane == 0) { wp[wid] = __popcll(bp); wn[wid] = __popcll(bn); }
    __syncthreads();
    if (tid == 0) {
        unsigned int p = wp[0] + wp[1] + wp[2] + wp[3];
        unsigned int n = wn[0] + wn[1] + wn[2] + wn[3];
        blk_cnt[img * NBLK + blk] = (p << 16) | n;
    }
}

// ============ K3: select + per-block self-prefix (round-9/10 proven) ============
__global__ __launch_bounds__(256) void k3_select(
    const unsigned char* __restrict__ packed,
    const unsigned int* __restrict__ blk_cnt,
    int* __restrict__ sel, int* __restrict__ sel_count) {
    const int img = blockIdx.y, blk = blockIdx.x;
    const int tid = threadIdx.x;
    const int lane = tid & 63, wid = tid >> 6;
    __shared__ unsigned long long sscan[8];
    __shared__ int wcnt[8];

    unsigned long long tot = 0ULL, pre = 0ULL;
    const int j0 = tid * 3;
    #pragma unroll
    for (int j = 0; j < 3; j++) {
        int i = j0 + j;
        if (i < NBLK) {
            unsigned u = blk_cnt[img * NBLK + i];
            unsigned long long w = ((unsigned long long)(u >> 16) << 32) | (u & 0xFFFFu);
            tot += w;
            if (i < blk) pre += w;
        }
    }
    #pragma unroll
    for (int o = 32; o > 0; o >>= 1) {
        tot += __shfl_down(tot, o);
        pre += __shfl_down(pre, o);
    }
    if (lane == 0) { sscan[wid] = tot; sscan[4 + wid] = pre; }
    __syncthreads();
    unsigned long long tota = sscan[0] + sscan[1] + sscan[2] + sscan[3];
    unsigned long long prea = sscan[4] + sscan[5] + sscan[6] + sscan[7];
    int tp = (int)(tota >> 32), tn = (int)(tota & 0xFFFFFFFFull);
    int npos = min(tp, 128), capn = 256 - npos;
    if (blk == 0 && tid == 0) sel_count[img] = npos + min(tn, capn);
    int base_p = (int)(prea >> 32), base_n = (int)(prea & 0xFFFFFFFFull);

    const int a = blk * 256 + tid;
    const bool act = a < A_TOTAL;
    int code = act ? (packed[(size_t)img * A_TOTAL + a] >> 5) : 2;
    const bool isp = act && code == 1;
    const bool isn = act && code == 0;
    unsigned long long bp = __ballot(isp);
    unsigned long long bn = __ballot(isn);
    if (lane == 0) { wcnt[wid] = __popcll(bp); wcnt[4 + wid] = __popcll(bn); }
    __syncthreads();
    const unsigned long long mlt = (1ULL << lane) - 1ULL;
    int rp = __popcll(bp & mlt), rn = __popcll(bn & mlt);
    for (int w = 0; w < 4; w++)
        if (w < wid) { rp += wcnt[w]; rn += wcnt[4 + w]; }
    if (isp) { int r = base_p + rp; if (r < npos) sel[img * 256 + r] = a | (1 << 30); }
    if (isn) { int r = base_n + rn; if (r < capn) sel[img * 256 + npos + r] = a; }
}

// ============ K4: conv partials — 16 anchors x 16-ci chunk (TRM=144) per block ============
__global__ __launch_bounds__(256) void k_convT16A(
    const float* __restrict__ f0, const float* __restrict__ f1,
    const float* __restrict__ f2, const float* __restrict__ f3,
    const float* __restrict__ f4,
    const float* __restrict__ wt,
    const int* __restrict__ sel, const int* __restrict__ sel_count,
    float* __restrict__ xpart) {
    const int img = blockIdx.z;          // grid (16, 16, 2)
    const int chunk = blockIdx.y;
    const int slot0 = blockIdx.x * 16;
    const int nsel = sel_count[img];
    if (slot0 >= nsel) return;

    __shared__ __align__(16) float patch[16][144];   // 9216 B
    __shared__ int sW[16], sY[16], sX[16], sAct[16];
    __shared__ const float* sfm[16];
    const int tid = threadIdx.x;

    if (tid < 16) {
        int slot = slot0 + tid;
        bool act = slot < nsel;
        int e = act ? sel[img * 256 + slot] : 0;
        int a = e & 0x3FFFFFFF;
        int W, aid, y, x, lvl;
        decode_anchor(a, W, aid, y, x, lvl);
        sW[tid] = W; sY[tid] = y; sX[tid] = x; sAct[tid] = act ? 1 : 0;
        sfm[tid] = (lvl == 0 ? f0 : lvl == 1 ? f1 : lvl == 2 ? f2 : lvl == 3 ? f3 : f4);
    }
    __syncthreads();

    for (int p = tid; p < 16 * 144; p += 256) {
        int aa = p / 144;
        int idx = p - aa * 144;
        int cil = idx / 9;
        int r = idx - cil * 9;
        int ky = r / 3, kx = r - ky * 3;
        int W = sW[aa];
        int yy = sY[aa] + ky - 1, xx = sX[aa] + kx - 1;
        float v = 0.f;
        if (sAct[aa] && yy >= 0 && yy < W && xx >= 0 && xx < W) {
            int ci = chunk * 16 + cil;
            v = sfm[aa][(((size_t)img * 256 + ci) * W + yy) * W + xx];
        }
        patch[aa][idx] = v;
    }
    __syncthreads();

    const int c = tid;
    const float4* wt4 = (const float4*)wt + (size_t)(chunk * 36) * 256 + c;
    float acc[16];
    #pragma unroll
    for (int aa = 0; aa < 16; aa++) acc[aa] = 0.f;
    #pragma unroll 2
    for (int i = 0; i < 36; i++) {
        float4 w = wt4[(size_t)i * 256];     // 1KB contiguous per wave
        #pragma unroll
        for (int aa = 0; aa < 16; aa++) {
            float4 q = ((const float4*)patch[aa])[i];   // uniform addr -> broadcast
            acc[aa] += w.x * q.x + w.y * q.y + w.z * q.z + w.w * q.w;
        }
    }
    #pragma unroll
    for (int aa = 0; aa < 16; aa++) {
        int slot = slot0 + aa;
        if (slot < nsel)
            xpart[(((size_t)img * 16 + chunk) * 256 + slot) * 256 + c] = acc[aa];
    }
}

// ============ K5: reduce 16 chunks + heads + per-anchor losses (round-10 proven) ============
__global__ __launch_bounds__(256) void k_post16(
    const float* __restrict__ xpart,
    const float* __restrict__ anchors, const float* __restrict__ gt,
    const float* __restrict__ b_in,
    const float* __restrict__ w_obj, const float* __restrict__ b_obj,
    const float* __restrict__ w_del, const float* __restrict__ b_del,
    const unsigned char* __restrict__ packed,
    const int* __restrict__ sel, const int* __restrict__ sel_count,
    float* __restrict__ lossbuf) {
    const int img = blockIdx.y;
    const int slot = blockIdx.x;
    const int nsel = sel_count[img];
    if (slot >= nsel) return;
    const int e = sel[img * 256 + slot];
    const int is_pos = (e >> 30) & 1;
    const int a = e & 0x3FFFFFFF;
    int W, aid, y, x, lvl;
    decode_anchor(a, W, aid, y, x, lvl);

    const int c = threadIdx.x;
    float s = b_in[c];
    #pragma unroll
    for (int ch = 0; ch < 16; ch++)
        s += xpart[(((size_t)img * 16 + ch) * 256 + slot) * 256 + c];
    float xf = fmaxf(s, 0.f);

    float part[5];
    part[0] = xf * w_obj[aid * 256 + c];
    #pragma unroll
    for (int j = 0; j < 4; j++) part[1 + j] = xf * w_del[(aid * 4 + j) * 256 + c];
    const int lane = c & 63, wid = c >> 6;
    __shared__ float red[5][4];
    #pragma unroll
    for (int o = 32; o > 0; o >>= 1)
        #pragma unroll
        for (int j = 0; j < 5; j++) part[j] += __shfl_down(part[j], o);
    if (lane == 0)
        #pragma unroll
        for (int j = 0; j < 5; j++) red[j][wid] = part[j];
    __syncthreads();

    if (c == 0) {
        float logit = red[0][0] + red[0][1] + red[0][2] + red[0][3] + b_obj[aid];
        float tgt = is_pos ? 1.f : 0.f;
        float bce = fmaxf(logit, 0.f) - logit * tgt + log1pf(expf(-fabsf(logit)));
        float l1 = 0.f;
        if (is_pos) {
            float d[4];
            #pragma unroll
            for (int j = 0; j < 4; j++)
                d[j] = red[1 + j][0] + red[1 + j][1] + red[1 + j][2] + red[1 + j][3] + b_del[aid * 4 + j];
            int m = packed[(size_t)img * A_TOTAL + a] & 31;
            const float* sp = anchors + (size_t)a * 4;
            const float* t = gt + (size_t)(img * NGT + m) * 4;
            float sw = sp[2] - sp[0], sh = sp[3] - sp[1];
            float scx = sp[0] + 0.5f * sw, scy = sp[1] + 0.5f * sh;
            float tw = t[2] - t[0], th = t[3] - t[1];
            float tcx = t[0] + 0.5f * tw, tcy = t[1] + 0.5f * th;
            float g0 = (tcx - scx) / sw, g1 = (tcy - scy) / sh;
            float g2 = logf(tw / sw),    g3 = logf(th / sh);
            l1 = fabsf(d[0] - g0) + fabsf(d[1] - g1) + fabsf(d[2] - g2) + fabsf(d[3] - g3);
        }
        lossbuf[(img * 256 + slot) * 2 + 0] = bce;
        lossbuf[(img * 256 + slot) * 2 + 1] = l1;
    }
}

// ============ K6: deterministic final reduction ============
__global__ void k_final(const float* __restrict__ lossbuf,
                        const int* __restrict__ sel_count,
                        float* __restrict__ out) {
    const int t = threadIdx.x;      // 512 threads
    const int img = t >> 8, slot = t & 255;
    float bce = 0.f, l1 = 0.f;
    if (slot < sel_count[img]) {
        bce = lossbuf[t * 2 + 0];
        l1  = lossbuf[t * 2 + 1];
    }
    const int lane = t & 63, wid = t >> 6;
    #pragma unroll
    for (int o = 32; o > 0; o >>= 1) {
        bce += __shfl_down(bce, o);
        l1  += __shfl_down(l1, o);
    }
    __shared__ float rb[8], rl[8];
    if (lane == 0) { rb[wid] = bce; rl[wid] = l1; }
    __syncthreads();
    if (t == 0) {
        float sb = 0.f, sl = 0.f;
        #pragma unroll
        for (int w = 0; w < 8; w++) { sb += rb[w]; sl += rl[w]; }
        out[0] = 0.5f * sb;
        out[1] = 0.5f * sl;
    }
}

// ============ minimal fallback (round-3 proven) for tiny workspace ============
__global__ void k_init(unsigned int* best, float* out) {
    int t = threadIdx.x;
    if (t < 2 * NGT) best[t] = 0u;
    if (t < 2) out[t] = 0.f;
}

__global__ void k_best(const float* __restrict__ anchors, const float* __restrict__ gt,
                       unsigned int* best) {
    const int img = blockIdx.y;
    __shared__ float sgt[NGT * 4];
    __shared__ float sred[4][NGT];
    const int tid = threadIdx.x;
    if (tid < NGT * 4) sgt[tid] = gt[img * NGT * 4 + tid];
    __syncthreads();
    float vmax[NGT];
    #pragma unroll
    for (int g = 0; g < NGT; g++) vmax[g] = 0.f;
    const int stride = gridDim.x * blockDim.x;
    for (int a = blockIdx.x * blockDim.x + tid; a < A_TOTAL; a += stride) {
        float4 ab = ((const float4*)anchors)[a];
        #pragma unroll
        for (int g = 0; g < NGT; g++) {
            float v = iou_one(ab.x, ab.y, ab.z, ab.w,
                              sgt[g * 4], sgt[g * 4 + 1], sgt[g * 4 + 2], sgt[g * 4 + 3]);
            vmax[g] = fmaxf(vmax[g], v);
        }
    }
    const int lane = tid & 63, wid = tid >> 6;
    #pragma unroll
    for (int g = 0; g < NGT; g++) {
        float v = vmax[g];
        #pragma unroll
        for (int o = 32; o > 0; o >>= 1) v = fmaxf(v, __shfl_down(v, o));
        if (lane == 0) sred[wid][g] = v;
    }
    __syncthreads();
    if (tid < NGT) {
        float v = fmaxf(fmaxf(sred[0][tid], sred[1][tid]),
                        fmaxf(sred[2][tid], sred[3][tid]));
        atomicMax(&best[img * NGT + tid], __float_as_uint(v));
    }
}

__global__ void k_label_old(const float* __restrict__ anchors, const float* __restrict__ gt,
                            const unsigned int* __restrict__ best,
                            unsigned char* packed, unsigned int* blk_cnt) {
    const int img = blockIdx.y;
    __shared__ float sgt[NGT * 4];
    __shared__ unsigned int sbest[NGT];
    __shared__ int wp[4], wn[4];
    const int tid = threadIdx.x;
    if (tid < NGT * 4) sgt[tid] = gt[img * NGT * 4 + tid];
    if (tid < NGT) sbest[tid] = best[img * NGT + tid];
    __syncthreads();
    const int a = blockIdx.x * blockDim.x + tid;
    const bool act = a < A_TOTAL;
    int code = 2;
    if (act) {
        float4 ab = ((const float4*)anchors)[a];
        float mval = -1.f; int arg = 0; bool lq = false;
        #pragma unroll
        for (int g = 0; g < NGT; g++) {
            float v = iou_one(ab.x, ab.y, ab.z, ab.w,
                              sgt[g * 4], sgt[g * 4 + 1], sgt[g * 4 + 2], sgt[g * 4 + 3]);
            if (v > mval) { mval = v; arg = g; }
            if (__float_as_uint(v) == sbest[g] && v > 0.f) lq = true;
        }
        if (lq || mval >= 0.7f) code = 1;
        else if (mval < 0.3f)   code = 0;
        packed[(size_t)img * A_TOTAL + a] = (unsigned char)((code << 5) | arg);
    }
    unsigned long long bp = __ballot(act && code == 1);
    unsigned long long bn = __ballot(act && code == 0);
    const int lane = tid & 63, wid = tid >> 6;
    if (lane == 0) { wp[wid] = __popcll(bp); wn[wid] = __popcll(bn); }
    __syncthreads();
    if (tid == 0) {
        unsigned int p = wp[0] + wp[1] + wp[2] + wp[3];
        unsigned int n = wn[0] + wn[1] + wn[2] + wn[3];
        blk_cnt[img * NBLK + blockIdx.x] = (p << 16) | n;
    }
}

__global__ __launch_bounds__(256) void k_eval(
    const float* __restrict__ f0, const float* __restrict__ f1,
    const float* __restrict__ f2, const float* __restrict__ f3,
    const float* __restrict__ f4,
    const float* __restrict__ anchors, const float* __restrict__ gt,
    const float* __restrict__ w_in, const float* __restrict__ b_in,
    const float* __restrict__ w_obj, const float* __restrict__ b_obj,
    const float* __restrict__ w_del, const float* __restrict__ b_del,
    const unsigned char* __restrict__ packed,
    const int* __restrict__ sel, const int* __restrict__ sel_count,
    float* out) {
    const int img = blockIdx.x >> 6;
    const int slot0 = (blockIdx.x & 63) * 4;
    const int nsel = sel_count[img];
    if (slot0 >= nsel) return;

    __shared__ __align__(16) float patch[4][2304];
    __shared__ float red[4][5][4];
    __shared__ float lsum[2];
    const int c = threadIdx.x;
    if (c < 2) lsum[c] = 0.f;

    bool actv[4]; int av[4], aidv[4], isposv[4];
    #pragma unroll
    for (int aa = 0; aa < 4; aa++) {
        int slot = slot0 + aa;
        bool act = slot < nsel;
        actv[aa] = act;
        int e = act ? sel[img * 256 + slot] : 0;
        isposv[aa] = (e >> 30) & 1;
        int a = e & 0x3FFFFFFF;
        av[aa] = a;
        int W, aid, y, x, lvl;
        decode_anchor(a, W, aid, y, x, lvl);
        aidv[aa] = aid;
        const float* fm = lvl == 0 ? f0 : lvl == 1 ? f1 : lvl == 2 ? f2 : lvl == 3 ? f3 : f4;
        const float* ch = fm + ((size_t)img * 256 + c) * W * W;
        #pragma unroll
        for (int ky = 0; ky < 3; ky++)
            #pragma unroll
            for (int kx = 0; kx < 3; kx++) {
                int yy = y + ky - 1, xx = x + kx - 1;
                float v = (act && yy >= 0 && yy < W && xx >= 0 && xx < W) ? ch[yy * W + xx] : 0.f;
                patch[aa][c * 9 + ky * 3 + kx] = v;
            }
    }
    __syncthreads();

    const float bi = b_in[c];
    float acc0 = bi, acc1 = bi, acc2 = bi, acc3 = bi;
    const float4* wr = (const float4*)(w_in + (size_t)c * 2304);
    const float4* p0 = (const float4*)patch[0];
    const float4* p1 = (const float4*)patch[1];
    const float4* p2 = (const float4*)patch[2];
    const float4* p3 = (const float4*)patch[3];
    #pragma unroll 4
    for (int i = 0; i < 576; i++) {
        float4 w = wr[i];
        float4 q;
        q = p0[i]; acc0 += w.x * q.x + w.y * q.y + w.z * q.z + w.w * q.w;
        q = p1[i]; acc1 += w.x * q.x + w.y * q.y + w.z * q.z + w.w * q.w;
        q = p2[i]; acc2 += w.x * q.x + w.y * q.y + w.z * q.z + w.w * q.w;
        q = p3[i]; acc3 += w.x * q.x + w.y * q.y + w.z * q.z + w.w * q.w;
    }
    float xf[4] = { fmaxf(acc0, 0.f), fmaxf(acc1, 0.f), fmaxf(acc2, 0.f), fmaxf(acc3, 0.f) };

    float part[4][5];
    #pragma unroll
    for (int aa = 0; aa < 4; aa++) {
        part[aa][0] = xf[aa] * w_obj[aidv[aa] * 256 + c];
        #pragma unroll
        for (int j = 0; j < 4; j++)
            part[aa][1 + j] = xf[aa] * w_del[(aidv[aa] * 4 + j) * 256 + c];
    }
    const int lane = c & 63, wid = c >> 6;
    #pragma unroll
    for (int o = 32; o > 0; o >>= 1)
        #pragma unroll
        for (int aa = 0; aa < 4; aa++)
            #pragma unroll
            for (int j = 0; j < 5; j++)
                part[aa][j] += __shfl_down(part[aa][j], o);
    if (lane == 0)
        #pragma unroll
        for (int aa = 0; aa < 4; aa++)
            #pragma unroll
            for (int j = 0; j < 5; j++)
                red[aa][j][wid] = part[aa][j];
    __syncthreads();

    if (c < 4 && actv[c]) {
        const int aa = c;
        float logit = red[aa][0][0] + red[aa][0][1] + red[aa][0][2] + red[aa][0][3] + b_obj[aidv[aa]];
        float tgt = isposv[aa] ? 1.f : 0.f;
        float bce = fmaxf(logit, 0.f) - logit * tgt + log1pf(expf(-fabsf(logit)));
        atomicAdd(&lsum[0], bce);
        if (isposv[aa]) {
            float d[4];
            #pragma unroll
            for (int j = 0; j < 4; j++)
                d[j] = red[aa][1 + j][0] + red[aa][1 + j][1] + red[aa][1 + j][2] + red[aa][1 + j][3]
                       + b_del[aidv[aa] * 4 + j];
            int a = av[aa];
            int m = packed[(size_t)img * A_TOTAL + a] & 31;
            const float* s = anchors + (size_t)a * 4;
            const float* t = gt + (size_t)(img * NGT + m) * 4;
            float sw = s[2] - s[0], sh = s[3] - s[1];
            float scx = s[0] + 0.5f * sw, scy = s[1] + 0.5f * sh;
            float tw = t[2] - t[0], th = t[3] - t[1];
            float tcx = t[0] + 0.5f * tw, tcy = t[1] + 0.5f * th;
            float g0 = (tcx - scx) / sw, g1 = (tcy - scy) / sh;
            float g2 = logf(tw / sw),    g3 = logf(th / sh);
            float l1 = fabsf(d[0] - g0) + fabsf(d[1] - g1) + fabsf(d[2] - g2) + fabsf(d[3] - g3);
            atomicAdd(&lsum[1], l1);
        }
    }
    __syncthreads();
    if (c == 0) {
        atomicAdd(&out[0], 0.5f * lsum[0]);
        atomicAdd(&out[1], 0.5f * lsum[1]);
    }
}

extern "C" void kernel_launch(void* const* d_in, const int* in_sizes, int n_in,
                              void* d_out, int out_size, void* d_ws, size_t ws_size,
                              hipStream_t stream) {
    const float* f_p6 = (const float*)d_in[0];
    const float* f_p5 = (const float*)d_in[1];
    const float* f_p4 = (const float*)d_in[2];
    const float* f_p3 = (const float*)d_in[3];
    const float* f_p2 = (const float*)d_in[4];
    const float* anchors = (const float*)d_in[5];
    const float* gt      = (const float*)d_in[6];
    const float* w_in  = (const float*)d_in[7];
    const float* b_in  = (const float*)d_in[8];
    const float* w_obj = (const float*)d_in[9];
    const float* b_obj = (const float*)d_in[10];
    const float* w_del = (const float*)d_in[11];
    const float* b_del = (const float*)d_in[12];
    float* out = (float*)d_out;
    char* ws = (char*)d_ws;

    // workspace layout (round-10 offsets)
    unsigned int* best    = (unsigned int*)(ws + 0);        // 160 B
    int* sel_count        = (int*)(ws + 168);               // 8 B
    int* sel              = (int*)(ws + 192);               // 2048 B
    unsigned int* blk_cnt = (unsigned int*)(ws + 2240);     // 5000 B
    unsigned char* packed = (unsigned char*)(ws + 17344);   // 319764 B
    float* lossbuf        = (float*)(ws + 337152);          // 4096 B
    float* mv             = (float*)(ws + 341248);          // 1279056 B
    unsigned* aux         = (unsigned*)(ws + 1620352);      // 1279056 B
    float* pmax           = (float*)(ws + 2899456);         // 100000 B
    float* xpart          = (float*)(ws + 2999552);         // 16*2*256*256*4 = 8388608 B
    float* wt             = (float*)(ws + 11388160);        // 2359296 B
    const size_t WS_NEED  = 13747456;

    if (ws_size >= WS_NEED) {
        // Round-10 proven 7-launch pipeline + ANB=16 conv (round-11's one good piece).
        // Lessons fixed: no grid barriers (r8), no per-block re-reduce (r9),
        // no per-block device fences (r11). Launch boundary = cheap sync (~2 µs).
        k1_bmax_wtrans<<<dim3(NBLK + WTBLK, 2), 256, 0, stream>>>(anchors, gt, w_in,
                                                                  pmax, mv, aux, wt);
        k_bred<<<dim3(NGT, 2), 256, 0, stream>>>(pmax, best);
        k2_label<<<dim3(NBLK, 2), 256, 0, stream>>>(mv, aux, pmax, best, packed, blk_cnt);
        k3_select<<<dim3(NBLK, 2), 256, 0, stream>>>(packed, blk_cnt, sel, sel_count);
        k_convT16A<<<dim3(16, 16, 2), 256, 0, stream>>>(f_p6, f_p5, f_p4, f_p3, f_p2,
                                                        wt, sel, sel_count, xpart);
        k_post16<<<dim3(256, 2), 256, 0, stream>>>(xpart, anchors, gt, b_in,
                                                   w_obj, b_obj, w_del, b_del,
                                                   packed, sel, sel_count, lossbuf);
        k_final<<<1, 512, 0, stream>>>(lossbuf, sel_count, out);
    } else {
        // tiny-workspace fallback (round-3 proven)
        k_init<<<1, 64, 0, stream>>>(best, out);
        k_best<<<dim3(64, 2), 256, 0, stream>>>(anchors, gt, best);
        k_label_old<<<dim3(NBLK, 2), 256, 0, stream>>>(anchors, gt, best, packed, blk_cnt);
        k3_select<<<dim3(NBLK, 2), 256, 0, stream>>>(packed, blk_cnt, sel, sel_count);
        k_eval<<<128, 256, 0, stream>>>(f_p6, f_p5, f_p4, f_p3, f_p2,
                                        anchors, gt, w_in, b_in, w_obj, b_obj,
                                        w_del, b_del, packed, sel, sel_count, out);
    }
}

// Round 13
// 63.253 us; speedup vs baseline: 1.9320x; 1.1021x over previous
//
#include <hip/hip_runtime.h>
#include <hip/hip_bf16.h>
#include <math.h>

#define A_TOTAL 159882
#define NGT 20
#define NBLK 625   // ceil(A_TOTAL/256)
#define WTBLK 288  // extra blocks (x2 imgs) for weight transpose in K1

// level geometry: p6(13) p5(25) p4(50) p3(100) p2(200), 3 anchors/pos
// cumulative anchor offsets: 0, 507, 2382, 9882, 39882, 159882
//
// Config ledger (measured):
//   r8:  software grid barrier        -> 608 µs  NEVER (spin + fence)
//   r11: per-block device fence       -> +56 µs  NEVER (1250 fences)
//   r9:  per-block 50KB best-re-reduce-> costs > 2 launches
//   conv block count: 512 blk = 51/70 µs (r5/r12), 1024 blk = best (r6..r10)
//   r10 (this config) = 63.1 µs  <- best measured

__device__ __forceinline__ float iou_one(float ax1, float ay1, float ax2, float ay2,
                                         float gx1, float gy1, float gx2, float gy2) {
    float a1 = (ax2 - ax1) * (ay2 - ay1);
    float a2 = (gx2 - gx1) * (gy2 - gy1);
    float ltx = fmaxf(ax1, gx1), lty = fmaxf(ay1, gy1);
    float rbx = fminf(ax2, gx2), rby = fminf(ay2, gy2);
    float w = fmaxf(rbx - ltx, 0.f), h = fmaxf(rby - lty, 0.f);
    float inter = w * h;
    return inter / (a1 + a2 - inter);
}

__device__ __forceinline__ void decode_anchor(int a, int& W, int& aid, int& y, int& x, int& lvl) {
    int off;
    if      (a < 507)   { off = 0;     W = 13;  lvl = 0; }
    else if (a < 2382)  { off = 507;   W = 25;  lvl = 1; }
    else if (a < 9882)  { off = 2382;  W = 50;  lvl = 2; }
    else if (a < 39882) { off = 9882;  W = 100; lvl = 3; }
    else                { off = 39882; W = 200; lvl = 4; }
    int rel = a - off;
    aid = rel % 3;
    int pos = rel / 3;
    y = pos / W; x = pos % W;
}

// ============ K1: wtrans (blocks >= NBLK) ∥ bmax + per-anchor mv/aux (blocks < NBLK) ============
__global__ __launch_bounds__(256) void k1_bmax_wtrans(
    const float* __restrict__ anchors, const float* __restrict__ gt,
    const float* __restrict__ w_in,
    float* __restrict__ pmax, float* __restrict__ mv, unsigned* __restrict__ aux,
    float* __restrict__ wt) {
    const int bx = blockIdx.x, img = blockIdx.y;
    const int tid = threadIdx.x;
    if (bx >= NBLK) {
        int idx = ((bx - NBLK) * 2 + img) * 256 + tid;   // 0..147455
        int co = idx / 576, k4 = idx - co * 576;
        float4 v = *(const float4*)(w_in + (size_t)co * 2304 + k4 * 4);
        ((float4*)wt)[(size_t)k4 * 256 + co] = v;
        return;
    }
    __shared__ float sgt[NGT * 4];
    __shared__ float sred[4][NGT];
    __shared__ float pblk[NGT];
    if (tid < NGT * 4) sgt[tid] = gt[img * NGT * 4 + tid];
    __syncthreads();
    const int a = bx * 256 + tid;
    const bool act = a < A_TOTAL;
    float4 ab = make_float4(0.f, 0.f, 1.f, 1.f);
    if (act) ab = ((const float4*)anchors)[a];
    const int lane = tid & 63, wid = tid >> 6;
    float v[NGT];
    float mval = -1.f; int arg = 0;
    #pragma unroll
    for (int g = 0; g < NGT; g++) {
        float u = act ? iou_one(ab.x, ab.y, ab.z, ab.w,
                                sgt[g*4], sgt[g*4+1], sgt[g*4+2], sgt[g*4+3]) : 0.f;
        v[g] = u;
        if (u > mval) { mval = u; arg = g; }
    }
    #pragma unroll
    for (int g = 0; g < NGT; g++) {
        float u = v[g];
        #pragma unroll
        for (int o = 32; o > 0; o >>= 1) u = fmaxf(u, __shfl_down(u, o));
        if (lane == 0) sred[wid][g] = u;
    }
    __syncthreads();
    if (tid < NGT) {
        float u = fmaxf(fmaxf(sred[0][tid], sred[1][tid]),
                        fmaxf(sred[2][tid], sred[3][tid]));
        pblk[tid] = u;
        pmax[((size_t)img * NBLK + bx) * NGT + tid] = u;
    }
    __syncthreads();
    if (act) {
        unsigned mask = 0;
        #pragma unroll
        for (int g = 0; g < NGT; g++)
            if (v[g] == pblk[g] && v[g] > 0.f) mask |= (1u << g);
        mv[(size_t)img * A_TOTAL + a] = mval;
        aux[(size_t)img * A_TOTAL + a] = (mask << 5) | (unsigned)arg;
    }
}

// ============ K1b: tree-reduce 625 partials per (img, gt) -> best ============
__global__ void k_bred(const float* __restrict__ pmax, unsigned int* __restrict__ best) {
    const int g = blockIdx.x, img = blockIdx.y;
    const int tid = threadIdx.x;   // 256
    float v = 0.f;
    for (int i = tid; i < NBLK; i += 256)
        v = fmaxf(v, pmax[((size_t)img * NBLK + i) * NGT + g]);
    const int lane = tid & 63, wid = tid >> 6;
    #pragma unroll
    for (int o = 32; o > 0; o >>= 1) v = fmaxf(v, __shfl_down(v, o));
    __shared__ float r[4];
    if (lane == 0) r[wid] = v;
    __syncthreads();
    if (tid == 0)
        best[img * NGT + g] = __float_as_uint(fmaxf(fmaxf(r[0], r[1]), fmaxf(r[2], r[3])));
}

// ============ K2: label from stored mv/aux (no IoU recompute) ============
__global__ __launch_bounds__(256) void k2_label(
    const float* __restrict__ mv, const unsigned* __restrict__ aux,
    const float* __restrict__ pmax, const unsigned int* __restrict__ best,
    unsigned char* __restrict__ packed, unsigned int* __restrict__ blk_cnt) {
    const int img = blockIdx.y, blk = blockIdx.x;
    const int tid = threadIdx.x;
    const int lane = tid & 63, wid = tid >> 6;
    __shared__ float sbest[NGT], pblk[NGT];
    __shared__ int wp[4], wn[4];
    if (tid < NGT) {
        sbest[tid] = __uint_as_float(best[img * NGT + tid]);
        pblk[tid]  = pmax[((size_t)img * NBLK + blk) * NGT + tid];
    }
    __syncthreads();
    const int a = blk * 256 + tid;
    const bool act = a < A_TOTAL;
    int code = 2;
    if (act) {
        float mval = mv[(size_t)img * A_TOTAL + a];
        unsigned ax = aux[(size_t)img * A_TOTAL + a];
        unsigned mask = ax >> 5;
        bool lq = false;
        #pragma unroll
        for (int g = 0; g < NGT; g++)
            if (((mask >> g) & 1u) && (pblk[g] == sbest[g])) lq = true;
        if (lq || mval >= 0.7f) code = 1;
        else if (mval < 0.3f)   code = 0;
        packed[(size_t)img * A_TOTAL + a] = (unsigned char)((code << 5) | (ax & 31u));
    }
    unsigned long long bp = __ballot(act && code == 1);
    unsigned long long bn = __ballot(act && code == 0);
    if (lane == 0) { wp[wid] = __popcll(bp); wn[wid] = __popcll(bn); }
    __syncthreads();
    if (tid == 0) {
        unsigned int p = wp[0] + wp[1] + wp[2] + wp[3];
        unsigned int n = wn[0] + wn[1] + wn[2] + wn[3];
        blk_cnt[img * NBLK + blk] = (p << 16) | n;
    }
}

// ============ K3: select + per-block self-prefix ============
__global__ __launch_bounds__(256) void k3_select(
    const unsigned char* __restrict__ packed,
    const unsigned int* __restrict__ blk_cnt,
    int* __restrict__ sel, int* __restrict__ sel_count) {
    const int img = blockIdx.y, blk = blockIdx.x;
    const int tid = threadIdx.x;
    const int lane = tid & 63, wid = tid >> 6;
    __shared__ unsigned long long sscan[8];
    __shared__ int wcnt[8];

    unsigned long long tot = 0ULL, pre = 0ULL;
    const int j0 = tid * 3;
    #pragma unroll
    for (int j = 0; j < 3; j++) {
        int i = j0 + j;
        if (i < NBLK) {
            unsigned u = blk_cnt[img * NBLK + i];
            unsigned long long w = ((unsigned long long)(u >> 16) << 32) | (u & 0xFFFFu);
            tot += w;
            if (i < blk) pre += w;
        }
    }
    #pragma unroll
    for (int o = 32; o > 0; o >>= 1) {
        tot += __shfl_down(tot, o);
        pre += __shfl_down(pre, o);
    }
    if (lane == 0) { sscan[wid] = tot; sscan[4 + wid] = pre; }
    __syncthreads();
    unsigned long long tota = sscan[0] + sscan[1] + sscan[2] + sscan[3];
    unsigned long long prea = sscan[4] + sscan[5] + sscan[6] + sscan[7];
    int tp = (int)(tota >> 32), tn = (int)(tota & 0xFFFFFFFFull);
    int npos = min(tp, 128), capn = 256 - npos;
    if (blk == 0 && tid == 0) sel_count[img] = npos + min(tn, capn);
    int base_p = (int)(prea >> 32), base_n = (int)(prea & 0xFFFFFFFFull);

    const int a = blk * 256 + tid;
    const bool act = a < A_TOTAL;
    int code = act ? (packed[(size_t)img * A_TOTAL + a] >> 5) : 2;
    const bool isp = act && code == 1;
    const bool isn = act && code == 0;
    unsigned long long bp = __ballot(isp);
    unsigned long long bn = __ballot(isn);
    if (lane == 0) { wcnt[wid] = __popcll(bp); wcnt[4 + wid] = __popcll(bn); }
    __syncthreads();
    const unsigned long long mlt = (1ULL << lane) - 1ULL;
    int rp = __popcll(bp & mlt), rn = __popcll(bn & mlt);
    for (int w = 0; w < 4; w++)
        if (w < wid) { rp += wcnt[w]; rn += wcnt[4 + w]; }
    if (isp) { int r = base_p + rp; if (r < npos) sel[img * 256 + r] = a | (1 << 30); }
    if (isn) { int r = base_n + rn; if (r < capn) sel[img * 256 + npos + r] = a; }
}

// ============ K4: conv partials — 8 anchors x 16-ci chunk (TRM=144), 1024 blocks ============
__global__ __launch_bounds__(256) void k_convT16(
    const float* __restrict__ f0, const float* __restrict__ f1,
    const float* __restrict__ f2, const float* __restrict__ f3,
    const float* __restrict__ f4,
    const float* __restrict__ wt,
    const int* __restrict__ sel, const int* __restrict__ sel_count,
    float* __restrict__ xpart) {
    const int img = blockIdx.z;          // grid (32, 16, 2)
    const int chunk = blockIdx.y;
    const int slot0 = blockIdx.x * 8;
    const int nsel = sel_count[img];
    if (slot0 >= nsel) return;

    __shared__ __align__(16) float patch[8][144];    // 4608 B
    __shared__ int sW[8], sY[8], sX[8], sAct[8];
    __shared__ const float* sfm[8];
    const int tid = threadIdx.x;

    if (tid < 8) {
        int slot = slot0 + tid;
        bool act = slot < nsel;
        int e = act ? sel[img * 256 + slot] : 0;
        int a = e & 0x3FFFFFFF;
        int W, aid, y, x, lvl;
        decode_anchor(a, W, aid, y, x, lvl);
        sW[tid] = W; sY[tid] = y; sX[tid] = x; sAct[tid] = act ? 1 : 0;
        sfm[tid] = (lvl == 0 ? f0 : lvl == 1 ? f1 : lvl == 2 ? f2 : lvl == 3 ? f3 : f4);
    }
    __syncthreads();

    for (int p = tid; p < 8 * 144; p += 256) {
        int aa = p / 144;
        int idx = p - aa * 144;
        int cil = idx / 9;
        int r = idx - cil * 9;
        int ky = r / 3, kx = r - ky * 3;
        int W = sW[aa];
        int yy = sY[aa] + ky - 1, xx = sX[aa] + kx - 1;
        float v = 0.f;
        if (sAct[aa] && yy >= 0 && yy < W && xx >= 0 && xx < W) {
            int ci = chunk * 16 + cil;
            v = sfm[aa][(((size_t)img * 256 + ci) * W + yy) * W + xx];
        }
        patch[aa][idx] = v;
    }
    __syncthreads();

    const int c = tid;
    const float4* wt4 = (const float4*)wt + (size_t)(chunk * 36) * 256 + c;
    float acc[8] = {0.f, 0.f, 0.f, 0.f, 0.f, 0.f, 0.f, 0.f};
    #pragma unroll 4
    for (int i = 0; i < 36; i++) {
        float4 w = wt4[(size_t)i * 256];     // 1KB contiguous per wave
        #pragma unroll
        for (int aa = 0; aa < 8; aa++) {
            float4 q = ((const float4*)patch[aa])[i];   // uniform addr -> broadcast
            acc[aa] += w.x * q.x + w.y * q.y + w.z * q.z + w.w * q.w;
        }
    }
    #pragma unroll
    for (int aa = 0; aa < 8; aa++) {
        int slot = slot0 + aa;
        if (slot < nsel)
            xpart[(((size_t)img * 16 + chunk) * 256 + slot) * 256 + c] = acc[aa];
    }
}

// ============ K5: reduce 16 chunks + heads + per-anchor losses ============
__global__ __launch_bounds__(256) void k_post16(
    const float* __restrict__ xpart,
    const float* __restrict__ anchors, const float* __restrict__ gt,
    const float* __restrict__ b_in,
    const float* __restrict__ w_obj, const float* __restrict__ b_obj,
    const float* __restrict__ w_del, const float* __restrict__ b_del,
    const unsigned char* __restrict__ packed,
    const int* __restrict__ sel, const int* __restrict__ sel_count,
    float* __restrict__ lossbuf) {
    const int img = blockIdx.y;
    const int slot = blockIdx.x;
    const int nsel = sel_count[img];
    if (slot >= nsel) return;
    const int e = sel[img * 256 + slot];
    const int is_pos = (e >> 30) & 1;
    const int a = e & 0x3FFFFFFF;
    int W, aid, y, x, lvl;
    decode_anchor(a, W, aid, y, x, lvl);

    const int c = threadIdx.x;
    float s = b_in[c];
    #pragma unroll
    for (int ch = 0; ch < 16; ch++)
        s += xpart[(((size_t)img * 16 + ch) * 256 + slot) * 256 + c];
    float xf = fmaxf(s, 0.f);

    float part[5];
    part[0] = xf * w_obj[aid * 256 + c];
    #pragma unroll
    for (int j = 0; j < 4; j++) part[1 + j] = xf * w_del[(aid * 4 + j) * 256 + c];
    const int lane = c & 63, wid = c >> 6;
    __shared__ float red[5][4];
    #pragma unroll
    for (int o = 32; o > 0; o >>= 1)
        #pragma unroll
        for (int j = 0; j < 5; j++) part[j] += __shfl_down(part[j], o);
    if (lane == 0)
        #pragma unroll
        for (int j = 0; j < 5; j++) red[j][wid] = part[j];
    __syncthreads();

    if (c == 0) {
        float logit = red[0][0] + red[0][1] + red[0][2] + red[0][3] + b_obj[aid];
        float tgt = is_pos ? 1.f : 0.f;
        float bce = fmaxf(logit, 0.f) - logit * tgt + log1pf(expf(-fabsf(logit)));
        float l1 = 0.f;
        if (is_pos) {
            float d[4];
            #pragma unroll
            for (int j = 0; j < 4; j++)
                d[j] = red[1 + j][0] + red[1 + j][1] + red[1 + j][2] + red[1 + j][3] + b_del[aid * 4 + j];
            int m = packed[(size_t)img * A_TOTAL + a] & 31;
            const float* sp = anchors + (size_t)a * 4;
            const float* t = gt + (size_t)(img * NGT + m) * 4;
            float sw = sp[2] - sp[0], sh = sp[3] - sp[1];
            float scx = sp[0] + 0.5f * sw, scy = sp[1] + 0.5f * sh;
            float tw = t[2] - t[0], th = t[3] - t[1];
            float tcx = t[0] + 0.5f * tw, tcy = t[1] + 0.5f * th;
            float g0 = (tcx - scx) / sw, g1 = (tcy - scy) / sh;
            float g2 = logf(tw / sw),    g3 = logf(th / sh);
            l1 = fabsf(d[0] - g0) + fabsf(d[1] - g1) + fabsf(d[2] - g2) + fabsf(d[3] - g3);
        }
        lossbuf[(img * 256 + slot) * 2 + 0] = bce;
        lossbuf[(img * 256 + slot) * 2 + 1] = l1;
    }
}

// ============ K6: deterministic final reduction ============
__global__ void k_final(const float* __restrict__ lossbuf,
                        const int* __restrict__ sel_count,
                        float* __restrict__ out) {
    const int t = threadIdx.x;      // 512 threads
    const int img = t >> 8, slot = t & 255;
    float bce = 0.f, l1 = 0.f;
    if (slot < sel_count[img]) {
        bce = lossbuf[t * 2 + 0];
        l1  = lossbuf[t * 2 + 1];
    }
    const int lane = t & 63, wid = t >> 6;
    #pragma unroll
    for (int o = 32; o > 0; o >>= 1) {
        bce += __shfl_down(bce, o);
        l1  += __shfl_down(l1, o);
    }
    __shared__ float rb[8], rl[8];
    if (lane == 0) { rb[wid] = bce; rl[wid] = l1; }
    __syncthreads();
    if (t == 0) {
        float sb = 0.f, sl = 0.f;
        #pragma unroll
        for (int w = 0; w < 8; w++) { sb += rb[w]; sl += rl[w]; }
        out[0] = 0.5f * sb;
        out[1] = 0.5f * sl;
    }
}

// ============ minimal fallback (round-3 proven) for tiny workspace ============
__global__ void k_init(unsigned int* best, float* out) {
    int t = threadIdx.x;
    if (t < 2 * NGT) best[t] = 0u;
    if (t < 2) out[t] = 0.f;
}

__global__ void k_best(const float* __restrict__ anchors, const float* __restrict__ gt,
                       unsigned int* best) {
    const int img = blockIdx.y;
    __shared__ float sgt[NGT * 4];
    __shared__ float sred[4][NGT];
    const int tid = threadIdx.x;
    if (tid < NGT * 4) sgt[tid] = gt[img * NGT * 4 + tid];
    __syncthreads();
    float vmax[NGT];
    #pragma unroll
    for (int g = 0; g < NGT; g++) vmax[g] = 0.f;
    const int stride = gridDim.x * blockDim.x;
    for (int a = blockIdx.x * blockDim.x + tid; a < A_TOTAL; a += stride) {
        float4 ab = ((const float4*)anchors)[a];
        #pragma unroll
        for (int g = 0; g < NGT; g++) {
            float v = iou_one(ab.x, ab.y, ab.z, ab.w,
                              sgt[g * 4], sgt[g * 4 + 1], sgt[g * 4 + 2], sgt[g * 4 + 3]);
            vmax[g] = fmaxf(vmax[g], v);
        }
    }
    const int lane = tid & 63, wid = tid >> 6;
    #pragma unroll
    for (int g = 0; g < NGT; g++) {
        float v = vmax[g];
        #pragma unroll
        for (int o = 32; o > 0; o >>= 1) v = fmaxf(v, __shfl_down(v, o));
        if (lane == 0) sred[wid][g] = v;
    }
    __syncthreads();
    if (tid < NGT) {
        float v = fmaxf(fmaxf(sred[0][tid], sred[1][tid]),
                        fmaxf(sred[2][tid], sred[3][tid]));
        atomicMax(&best[img * NGT + tid], __float_as_uint(v));
    }
}

__global__ void k_label_old(const float* __restrict__ anchors, const float* __restrict__ gt,
                            const unsigned int* __restrict__ best,
                            unsigned char* packed, unsigned int* blk_cnt) {
    const int img = blockIdx.y;
    __shared__ float sgt[NGT * 4];
    __shared__ unsigned int sbest[NGT];
    __shared__ int wp[4], wn[4];
    const int tid = threadIdx.x;
    if (tid < NGT * 4) sgt[tid] = gt[img * NGT * 4 + tid];
    if (tid < NGT) sbest[tid] = best[img * NGT + tid];
    __syncthreads();
    const int a = blockIdx.x * blockDim.x + tid;
    const bool act = a < A_TOTAL;
    int code = 2;
    if (act) {
        float4 ab = ((const float4*)anchors)[a];
        float mval = -1.f; int arg = 0; bool lq = false;
        #pragma unroll
        for (int g = 0; g < NGT; g++) {
            float v = iou_one(ab.x, ab.y, ab.z, ab.w,
                              sgt[g * 4], sgt[g * 4 + 1], sgt[g * 4 + 2], sgt[g * 4 + 3]);
            if (v > mval) { mval = v; arg = g; }
            if (__float_as_uint(v) == sbest[g] && v > 0.f) lq = true;
        }
        if (lq || mval >= 0.7f) code = 1;
        else if (mval < 0.3f)   code = 0;
        packed[(size_t)img * A_TOTAL + a] = (unsigned char)((code << 5) | arg);
    }
    unsigned long long bp = __ballot(act && code == 1);
    unsigned long long bn = __ballot(act && code == 0);
    const int lane = tid & 63, wid = tid >> 6;
    if (lane == 0) { wp[wid] = __popcll(bp); wn[wid] = __popcll(bn); }
    __syncthreads();
    if (tid == 0) {
        unsigned int p = wp[0] + wp[1] + wp[2] + wp[3];
        unsigned int n = wn[0] + wn[1] + wn[2] + wn[3];
        blk_cnt[img * NBLK + blockIdx.x] = (p << 16) | n;
    }
}

__global__ __launch_bounds__(256) void k_eval(
    const float* __restrict__ f0, const float* __restrict__ f1,
    const float* __restrict__ f2, const float* __restrict__ f3,
    const float* __restrict__ f4,
    const float* __restrict__ anchors, const float* __restrict__ gt,
    const float* __restrict__ w_in, const float* __restrict__ b_in,
    const float* __restrict__ w_obj, const float* __restrict__ b_obj,
    const float* __restrict__ w_del, const float* __restrict__ b_del,
    const unsigned char* __restrict__ packed,
    const int* __restrict__ sel, const int* __restrict__ sel_count,
    float* out) {
    const int img = blockIdx.x >> 6;
    const int slot0 = (blockIdx.x & 63) * 4;
    const int nsel = sel_count[img];
    if (slot0 >= nsel) return;

    __shared__ __align__(16) float patch[4][2304];
    __shared__ float red[4][5][4];
    __shared__ float lsum[2];
    const int c = threadIdx.x;
    if (c < 2) lsum[c] = 0.f;

    bool actv[4]; int av[4], aidv[4], isposv[4];
    #pragma unroll
    for (int aa = 0; aa < 4; aa++) {
        int slot = slot0 + aa;
        bool act = slot < nsel;
        actv[aa] = act;
        int e = act ? sel[img * 256 + slot] : 0;
        isposv[aa] = (e >> 30) & 1;
        int a = e & 0x3FFFFFFF;
        av[aa] = a;
        int W, aid, y, x, lvl;
        decode_anchor(a, W, aid, y, x, lvl);
        aidv[aa] = aid;
        const float* fm = lvl == 0 ? f0 : lvl == 1 ? f1 : lvl == 2 ? f2 : lvl == 3 ? f3 : f4;
        const float* ch = fm + ((size_t)img * 256 + c) * W * W;
        #pragma unroll
        for (int ky = 0; ky < 3; ky++)
            #pragma unroll
            for (int kx = 0; kx < 3; kx++) {
                int yy = y + ky - 1, xx = x + kx - 1;
                float v = (act && yy >= 0 && yy < W && xx >= 0 && xx < W) ? ch[yy * W + xx] : 0.f;
                patch[aa][c * 9 + ky * 3 + kx] = v;
            }
    }
    __syncthreads();

    const float bi = b_in[c];
    float acc0 = bi, acc1 = bi, acc2 = bi, acc3 = bi;
    const float4* wr = (const float4*)(w_in + (size_t)c * 2304);
    const float4* p0 = (const float4*)patch[0];
    const float4* p1 = (const float4*)patch[1];
    const float4* p2 = (const float4*)patch[2];
    const float4* p3 = (const float4*)patch[3];
    #pragma unroll 4
    for (int i = 0; i < 576; i++) {
        float4 w = wr[i];
        float4 q;
        q = p0[i]; acc0 += w.x * q.x + w.y * q.y + w.z * q.z + w.w * q.w;
        q = p1[i]; acc1 += w.x * q.x + w.y * q.y + w.z * q.z + w.w * q.w;
        q = p2[i]; acc2 += w.x * q.x + w.y * q.y + w.z * q.z + w.w * q.w;
        q = p3[i]; acc3 += w.x * q.x + w.y * q.y + w.z * q.z + w.w * q.w;
    }
    float xf[4] = { fmaxf(acc0, 0.f), fmaxf(acc1, 0.f), fmaxf(acc2, 0.f), fmaxf(acc3, 0.f) };

    float part[4][5];
    #pragma unroll
    for (int aa = 0; aa < 4; aa++) {
        part[aa][0] = xf[aa] * w_obj[aidv[aa] * 256 + c];
        #pragma unroll
        for (int j = 0; j < 4; j++)
            part[aa][1 + j] = xf[aa] * w_del[(aidv[aa] * 4 + j) * 256 + c];
    }
    const int lane = c & 63, wid = c >> 6;
    #pragma unroll
    for (int o = 32; o > 0; o >>= 1)
        #pragma unroll
        for (int aa = 0; aa < 4; aa++)
            #pragma unroll
            for (int j = 0; j < 5; j++)
                part[aa][j] += __shfl_down(part[aa][j], o);
    if (lane == 0)
        #pragma unroll
        for (int aa = 0; aa < 4; aa++)
            #pragma unroll
            for (int j = 0; j < 5; j++)
                red[aa][j][wid] = part[aa][j];
    __syncthreads();

    if (c < 4 && actv[c]) {
        const int aa = c;
        float logit = red[aa][0][0] + red[aa][0][1] + red[aa][0][2] + red[aa][0][3] + b_obj[aidv[aa]];
        float tgt = isposv[aa] ? 1.f : 0.f;
        float bce = fmaxf(logit, 0.f) - logit * tgt + log1pf(expf(-fabsf(logit)));
        atomicAdd(&lsum[0], bce);
        if (isposv[aa]) {
            float d[4];
            #pragma unroll
            for (int j = 0; j < 4; j++)
                d[j] = red[aa][1 + j][0] + red[aa][1 + j][1] + red[aa][1 + j][2] + red[aa][1 + j][3]
                       + b_del[aidv[aa] * 4 + j];
            int a = av[aa];
            int m = packed[(size_t)img * A_TOTAL + a] & 31;
            const float* s = anchors + (size_t)a * 4;
            const float* t = gt + (size_t)(img * NGT + m) * 4;
            float sw = s[2] - s[0], sh = s[3] - s[1];
            float scx = s[0] + 0.5f * sw, scy = s[1] + 0.5f * sh;
            float tw = t[2] - t[0], th = t[3] - t[1];
            float tcx = t[0] + 0.5f * tw, tcy = t[1] + 0.5f * th;
            float g0 = (tcx - scx) / sw, g1 = (tcy - scy) / sh;
            float g2 = logf(tw / sw),    g3 = logf(th / sh);
            float l1 = fabsf(d[0] - g0) + fabsf(d[1] - g1) + fabsf(d[2] - g2) + fabsf(d[3] - g3);
            atomicAdd(&lsum[1], l1);
        }
    }
    __syncthreads();
    if (c == 0) {
        atomicAdd(&out[0], 0.5f * lsum[0]);
        atomicAdd(&out[1], 0.5f * lsum[1]);
    }
}

extern "C" void kernel_launch(void* const* d_in, const int* in_sizes, int n_in,
                              void* d_out, int out_size, void* d_ws, size_t ws_size,
                              hipStream_t stream) {
    const float* f_p6 = (const float*)d_in[0];
    const float* f_p5 = (const float*)d_in[1];
    const float* f_p4 = (const float*)d_in[2];
    const float* f_p3 = (const float*)d_in[3];
    const float* f_p2 = (const float*)d_in[4];
    const float* anchors = (const float*)d_in[5];
    const float* gt      = (const float*)d_in[6];
    const float* w_in  = (const float*)d_in[7];
    const float* b_in  = (const float*)d_in[8];
    const float* w_obj = (const float*)d_in[9];
    const float* b_obj = (const float*)d_in[10];
    const float* w_del = (const float*)d_in[11];
    const float* b_del = (const float*)d_in[12];
    float* out = (float*)d_out;
    char* ws = (char*)d_ws;

    // workspace layout (round-10 offsets)
    unsigned int* best    = (unsigned int*)(ws + 0);        // 160 B
    int* sel_count        = (int*)(ws + 168);               // 8 B
    int* sel              = (int*)(ws + 192);               // 2048 B
    unsigned int* blk_cnt = (unsigned int*)(ws + 2240);     // 5000 B
    unsigned char* packed = (unsigned char*)(ws + 17344);   // 319764 B
    float* lossbuf        = (float*)(ws + 337152);          // 4096 B
    float* mv             = (float*)(ws + 341248);          // 1279056 B
    unsigned* aux         = (unsigned*)(ws + 1620352);      // 1279056 B
    float* pmax           = (float*)(ws + 2899456);         // 100000 B
    float* xpart          = (float*)(ws + 2999552);         // 16*2*256*256*4 = 8388608 B
    float* wt             = (float*)(ws + 11388160);        // 2359296 B
    const size_t WS_NEED  = 13747456;

    if (ws_size >= WS_NEED) {
        // Exact round-10 configuration — best measured (63.1 µs).
        k1_bmax_wtrans<<<dim3(NBLK + WTBLK, 2), 256, 0, stream>>>(anchors, gt, w_in,
                                                                  pmax, mv, aux, wt);
        k_bred<<<dim3(NGT, 2), 256, 0, stream>>>(pmax, best);
        k2_label<<<dim3(NBLK, 2), 256, 0, stream>>>(mv, aux, pmax, best, packed, blk_cnt);
        k3_select<<<dim3(NBLK, 2), 256, 0, stream>>>(packed, blk_cnt, sel, sel_count);
        k_convT16<<<dim3(32, 16, 2), 256, 0, stream>>>(f_p6, f_p5, f_p4, f_p3, f_p2,
                                                       wt, sel, sel_count, xpart);
        k_post16<<<dim3(256, 2), 256, 0, stream>>>(xpart, anchors, gt, b_in,
                                                   w_obj, b_obj, w_del, b_del,
                                                   packed, sel, sel_count, lossbuf);
        k_final<<<1, 512, 0, stream>>>(lossbuf, sel_count, out);
    } else {
        // tiny-workspace fallback (round-3 proven)
        k_init<<<1, 64, 0, stream>>>(best, out);
        k_best<<<dim3(64, 2), 256, 0, stream>>>(anchors, gt, best);
        k_label_old<<<dim3(NBLK, 2), 256, 0, stream>>>(anchors, gt, best, packed, blk_cnt);
        k3_select<<<dim3(NBLK, 2), 256, 0, stream>>>(packed, blk_cnt, sel, sel_count);
        k_eval<<<128, 256, 0, stream>>>(f_p6, f_p5, f_p4, f_p3, f_p2,
                                        anchors, gt, w_in, b_in, w_obj, b_obj,
                                        w_del, b_del, packed, sel, sel_count, out);
    }
}